// Round 5
// baseline (522.330 us; speedup 1.0000x reference)
//
#include <hip/hip_runtime.h>

#define N_TOK   524288
#define KC      256
#define D       32
#define EPSF    1e-6f
#define NBLK    1024               // 4 waves/block; 4096 global waves
#define BLKT    256
#define NWAVES  (NBLK * 4)
#define NSTRIP  (N_TOK / 16)       // 32768 strips of 16 tokens
#define SPW     (NSTRIP / NWAVES)  // 8 strips per wave
#define MARGIN  1e-3f              // >> 2e-5 sound error bound of the bf16x3 screen
#define BIGF    3.4e38f

typedef __attribute__((ext_vector_type(8))) short short8;
typedef __attribute__((ext_vector_type(4))) float f32x4;

__device__ __forceinline__ unsigned short f32_to_bf16_rne(float f) {
    unsigned int u = __float_as_uint(f);
    unsigned int r = u + 0x7fffu + ((u >> 16) & 1u);
    return (unsigned short)(r >> 16);
}
__device__ __forceinline__ float bf16_to_f32(unsigned short h) {
    return __uint_as_float(((unsigned int)h) << 16);
}

// ---------------- main kernel: MFMA screen + exact recheck + rotation ----------------
__global__ __launch_bounds__(BLKT) void vq_main(
    const float* __restrict__ x, const float* __restrict__ cb,
    float* __restrict__ out_rot, float* __restrict__ out_idx,
    float* __restrict__ ws_hist, float* __restrict__ out_cnt, int use_ws)
{
    // codebook bf16 hi/lo, padded rows (20 uints = 80B: 16B-aligned, 2-way banks max)
    __shared__ unsigned int cbh[KC][20];   // 20 KB (cols 0..15 used)
    __shared__ unsigned int cbl[KC][20];   // 20 KB
    __shared__ float c2s[KC];              // ||c||^2 exact pairwise (1 KB)
    __shared__ float hist[KC];             // 1 KB
    __shared__ float xs[4][16][36];        // per-wave x strip, fp32, padded (9.2 KB)
    __shared__ float x2w[4][16];           // per-wave exact ||x||^2
    __shared__ int   win[4][16];           // per-wave winners
    // total ~52.7 KB -> 3 blocks/CU

    const int tid  = threadIdx.x;
    const int lane = tid & 63;
    const int w    = tid >> 6;

    // ---- init: c2 exact (numpy pairwise) + bf16 hi/lo split of codebook ----
    {
#pragma clang fp contract(off)
        const float4* cb4 = (const float4*)(cb + (size_t)tid * D);
        float4 r[8];
#pragma unroll
        for (int j = 0; j < 8; j++) r[j] = cb4[j];
        float v[32];
#pragma unroll
        for (int j = 0; j < 8; j++) {
            v[4*j+0] = r[j].x; v[4*j+1] = r[j].y; v[4*j+2] = r[j].z; v[4*j+3] = r[j].w;
        }
        float t[32];
#pragma unroll
        for (int k = 0; k < 32; k++) t[k] = v[k] * v[k];
        float pr[8];
#pragma unroll
        for (int j = 0; j < 8; j++)
            pr[j] = ((t[j] + t[j + 8]) + t[j + 16]) + t[j + 24];
        c2s[tid] = ((pr[0] + pr[1]) + (pr[2] + pr[3])) + ((pr[4] + pr[5]) + (pr[6] + pr[7]));

        unsigned int hp[16], lp[16];
#pragma unroll
        for (int q = 0; q < 16; q++) { hp[q] = 0u; lp[q] = 0u; }
#pragma unroll
        for (int j = 0; j < 32; j++) {
            unsigned short h = f32_to_bf16_rne(v[j]);
            float lo = v[j] - bf16_to_f32(h);
            unsigned short l = f32_to_bf16_rne(lo);
            hp[j >> 1] |= ((unsigned int)h) << (16 * (j & 1));
            lp[j >> 1] |= ((unsigned int)l) << (16 * (j & 1));
        }
#pragma unroll
        for (int q = 0; q < 4; q++) {
            ((uint4*)&cbh[tid][0])[q] = make_uint4(hp[4*q], hp[4*q+1], hp[4*q+2], hp[4*q+3]);
            ((uint4*)&cbl[tid][0])[q] = make_uint4(lp[4*q], lp[4*q+1], lp[4*q+2], lp[4*q+3]);
        }
        hist[tid] = 0.f;
    }
    __syncthreads();

    const int col = lane & 15;     // A: token row / B: code col
    const int kc  = lane >> 4;     // k-chunk 0..3 (8 elems each)

    // per-lane c2 for its code column of each of the 16 code-tiles
    float c2r[16];
#pragma unroll
    for (int t = 0; t < 16; t++) c2r[t] = c2s[t * 16 + col];

    const int gw = blockIdx.x * 4 + w;

    for (int s = 0; s < SPW; ++s) {
        const int strip = gw + NWAVES * s;
        const int tb    = strip * 16;

        // ---- load A chunk (x[tb+col][kc*8 .. +7]), stage strip to LDS ----
        const float* xp = x + (size_t)(tb + col) * D + kc * 8;
        const float4 f0 = *(const float4*)xp;
        const float4 f1 = *(const float4*)(xp + 4);
        *(float4*)&xs[w][col][kc * 8]     = f0;
        *(float4*)&xs[w][col][kc * 8 + 4] = f1;

        // A fragments (hi/lo bf16), element e <-> k = kc*8+e
        short8 ah, al;
        {
            float xf[8] = {f0.x, f0.y, f0.z, f0.w, f1.x, f1.y, f1.z, f1.w};
#pragma unroll
            for (int j = 0; j < 8; j++) {
                unsigned short h = f32_to_bf16_rne(xf[j]);
                float lo = xf[j] - bf16_to_f32(h);
                ah[j] = (short)h;
                al[j] = (short)f32_to_bf16_rne(lo);
            }
        }

        // ---- exact ||x||^2 per token (numpy pairwise order, 4 lanes/token) ----
        {
#pragma clang fp contract(off)
            const int tok4 = lane >> 2, sub = lane & 3, base = lane & ~3;
            const float4 a = *(const float4*)&xs[w][tok4][sub * 8];
            const float4 b = *(const float4*)&xs[w][tok4][sub * 8 + 4];
            float sq[8] = {a.x*a.x, a.y*a.y, a.z*a.z, a.w*a.w,
                           b.x*b.x, b.y*b.y, b.z*b.z, b.w*b.w};
            float pr[8];
#pragma unroll
            for (int j = 0; j < 8; j++) {
                float t01 = sq[j] + __shfl_xor(sq[j], 1, 64);   // sub0: t[j]+t[j+8]
                float s2  = __shfl(sq[j], base + 2, 64);        // t[j+16]
                float s3  = __shfl(sq[j], base + 3, 64);        // t[j+24]
                pr[j] = (t01 + s2) + s3;
            }
            float v = ((pr[0]+pr[1]) + (pr[2]+pr[3])) + ((pr[4]+pr[5]) + (pr[6]+pr[7]));
            if (sub == 0) x2w[w][tok4] = v;
        }

        // ---- MFMA screen: 16 tiles of 16 tokens x 16 codes, K=32 in one shot ----
        float sarr[16][4];
        float mn[4] = {BIGF, BIGF, BIGF, BIGF};
#pragma unroll
        for (int t = 0; t < 16; ++t) {
            const int code = t * 16 + col;
            const short8 bh = *(const short8*)&cbh[code][kc * 4];
            const short8 bl = *(const short8*)&cbl[code][kc * 4];
            f32x4 acc = {0.f, 0.f, 0.f, 0.f};
            acc = __builtin_amdgcn_mfma_f32_16x16x32_bf16(al, bh, acc, 0, 0, 0);
            acc = __builtin_amdgcn_mfma_f32_16x16x32_bf16(ah, bl, acc, 0, 0, 0);
            acc = __builtin_amdgcn_mfma_f32_16x16x32_bf16(ah, bh, acc, 0, 0, 0);
#pragma unroll
            for (int r = 0; r < 4; ++r) {
                const float sv = __builtin_fmaf(-2.f, acc[r], c2r[t]);
                sarr[t][r] = sv;
                mn[r] = fminf(mn[r], sv);
            }
        }
        // per-row screen minimum across the 16 code-lanes
#pragma unroll
        for (int m = 1; m < 16; m <<= 1)
#pragma unroll
            for (int r = 0; r < 4; ++r)
                mn[r] = fminf(mn[r], __shfl_xor(mn[r], m, 64));

        // ---- exact recheck of candidates (reference-exact chain) ----
        float bE[4] = {BIGF, BIGF, BIGF, BIGF};
        int   bI[4] = {0x7fffffff, 0x7fffffff, 0x7fffffff, 0x7fffffff};
#pragma unroll
        for (int t = 0; t < 16; ++t)
#pragma unroll
            for (int r = 0; r < 4; ++r)
                if (sarr[t][r] <= mn[r] + MARGIN) {
                    const int code = t * 16 + col;
                    const int trow = kc * 4 + r;            // C row = token
                    const float* crow = cb + (size_t)code * D;
                    float acc = 0.f;
#pragma unroll
                    for (int q = 0; q < 8; ++q) {
                        const float4 xq = *(const float4*)&xs[w][trow][q * 4];
                        const float4 cq = *(const float4*)&crow[q * 4];
                        acc = __builtin_fmaf(xq.x, cq.x, acc);
                        acc = __builtin_fmaf(xq.y, cq.y, acc);
                        acc = __builtin_fmaf(xq.z, cq.z, acc);
                        acc = __builtin_fmaf(xq.w, cq.w, acc);
                    }
                    const float t2 = x2w[w][trow] - 2.0f * acc;  // 2*acc exact
                    const float d  = t2 + c2s[code];
                    if (d < bE[r] || (d == bE[r] && code < bI[r])) { bE[r] = d; bI[r] = code; }
                }
        // winner per token row: first-min tie-break across the 16 code-lanes
#pragma unroll
        for (int m = 1; m < 16; m <<= 1)
#pragma unroll
            for (int r = 0; r < 4; ++r) {
                const float ov = __shfl_xor(bE[r], m, 64);
                const int   oi = __shfl_xor(bI[r], m, 64);
                if (ov < bE[r] || (ov == bE[r] && oi < bI[r])) { bE[r] = ov; bI[r] = oi; }
            }
        if (col == 0)
#pragma unroll
            for (int r = 0; r < 4; ++r) win[w][kc * 4 + r] = bI[r];

        // ---- rotation epilogue (identical arithmetic to the passing kernel) ----
        {
            const int tok = lane >> 2, sub = lane & 3;
            const size_t gtok = (size_t)tb + tok;
            const int bi = win[w][tok];
            const float4* cg = (const float4*)(cb + (size_t)bi * D + sub * 8);
            const float4 ca = cg[0], cbv = cg[1];
            const float4 xa = *(const float4*)&xs[w][tok][sub * 8];
            const float4 xb = *(const float4*)&xs[w][tok][sub * 8 + 4];

            float xs8[8] = {xa.x, xa.y, xa.z, xa.w, xb.x, xb.y, xb.z, xb.w};
            float cs8[8] = {ca.x, ca.y, ca.z, ca.w, cbv.x, cbv.y, cbv.z, cbv.w};

            float px2 = 0.f, pc2 = 0.f;
#pragma unroll
            for (int j = 0; j < 8; j++) { px2 = fmaf(xs8[j], xs8[j], px2); pc2 = fmaf(cs8[j], cs8[j], pc2); }
            float x2 = px2 + __shfl_xor(px2, 1, 64); x2 += __shfl_xor(x2, 2, 64);
            float c2 = pc2 + __shfl_xor(pc2, 1, 64); c2 += __shfl_xor(c2, 2, 64);
            const float inx = 1.f / fmaxf(sqrtf(x2), EPSF);
            const float inc = 1.f / fmaxf(sqrtf(c2), EPSF);

            float us8[8], qs8[8], ws8[8];
            float pw2 = 0.f;
#pragma unroll
            for (int j = 0; j < 8; j++) {
                us8[j] = xs8[j] * inx;
                qs8[j] = cs8[j] * inc;
                ws8[j] = us8[j] + qs8[j];
                pw2 = fmaf(ws8[j], ws8[j], pw2);
            }
            float w2 = pw2 + __shfl_xor(pw2, 1, 64); w2 += __shfl_xor(w2, 2, 64);
            const float inw = 1.f / fmaxf(sqrtf(w2), EPSF);

            float pew = 0.f, peu = 0.f;
#pragma unroll
            for (int j = 0; j < 8; j++) {
                ws8[j] *= inw;
                pew = fmaf(xs8[j], ws8[j], pew);
                peu = fmaf(xs8[j], us8[j], peu);
            }
            float ew = pew + __shfl_xor(pew, 1, 64); ew += __shfl_xor(ew, 2, 64);
            float eu = peu + __shfl_xor(peu, 1, 64); eu += __shfl_xor(eu, 2, 64);

            float ro[8];
#pragma unroll
            for (int j = 0; j < 8; j++)
                ro[j] = xs8[j] - 2.f * ew * ws8[j] + 2.f * eu * qs8[j];

            float4* og = (float4*)(out_rot + gtok * D + sub * 8);
            og[0] = make_float4(ro[0], ro[1], ro[2], ro[3]);
            og[1] = make_float4(ro[4], ro[5], ro[6], ro[7]);

            if (sub == 0) {
                out_idx[gtok] = (float)bi;
                atomicAdd(&hist[bi], 1.f);
            }
        }
    }

    __syncthreads();
    // ---- flush per-block histogram ----
    if (use_ws) ws_hist[(size_t)blockIdx.x * KC + tid] = hist[tid];
    else        atomicAdd(&out_cnt[tid], hist[tid]);
}

// ---------------- tiny reduce: 1024 block-partials -> 256 counts ----------------
__global__ __launch_bounds__(256) void vq_reduce(const float* __restrict__ ws,
                                                 float* __restrict__ out_cnt)
{
    const int c = blockIdx.x * 8 + (threadIdx.x >> 5);  // code
    const int l = threadIdx.x & 31;                     // lane within code-group
    float s = 0.f;
    for (int b = l; b < NBLK; b += 32) s += ws[(size_t)b * KC + c];
#pragma unroll
    for (int m = 1; m < 32; m <<= 1) s += __shfl_xor(s, m, 64);
    if (l == 0) out_cnt[c] = s;
}

extern "C" void kernel_launch(void* const* d_in, const int* in_sizes, int n_in,
                              void* d_out, int out_size, void* d_ws, size_t ws_size,
                              hipStream_t stream)
{
    const float* x  = (const float*)d_in[0];
    const float* cb = (const float*)d_in[1];
    float* out      = (float*)d_out;
    float* out_rot  = out;                                   // [524288*32]
    float* out_idx  = out + (size_t)N_TOK * D;               // [524288] (indices as float)
    float* out_cnt  = out_idx + N_TOK;                       // [256]

    const size_t ws_need = (size_t)NBLK * KC * sizeof(float);
    const int use_ws = (ws_size >= ws_need) ? 1 : 0;
    if (!use_ws) hipMemsetAsync(out_cnt, 0, KC * sizeof(float), stream);

    vq_main<<<NBLK, BLKT, 0, stream>>>(x, cb, out_rot, out_idx,
                                       (float*)d_ws, out_cnt, use_ws);
    if (use_ws) vq_reduce<<<32, 256, 0, stream>>>((const float*)d_ws, out_cnt);
}

// Round 6
// 460.850 us; speedup vs baseline: 1.1334x; 1.1334x over previous
//
#include <hip/hip_runtime.h>
#include <hip/hip_fp16.h>

#define N_TOK   524288
#define KC      256
#define D       32
#define EPSF    1e-6f
#define TPB     64                 // tokens per block-tile
#define NTILES  (N_TOK / TPB)      // 8192
#define NBLK    768                // 3 blocks/CU
#define BLKT    256
#define MARGIN  5e-4f              // >= 2*screen_err(~1e-5) + f16 pack err(6.1e-5), 3.5x slack
#define BIGF    3.4e38f

typedef __attribute__((ext_vector_type(8))) short short8;
typedef __attribute__((ext_vector_type(4))) float f32x4;

static __device__ __forceinline__ unsigned short f32_to_bf16_rne(float f) {
    unsigned int u = __float_as_uint(f);
    unsigned int r = u + 0x7fffu + ((u >> 16) & 1u);
    return (unsigned short)(r >> 16);
}
static __device__ __forceinline__ float bf16_to_f32(unsigned short h) {
    return __uint_as_float(((unsigned int)h) << 16);
}
// monotone float->uint key (total order == float <)
static __device__ __forceinline__ unsigned fkey(float f) {
    unsigned b = __float_as_uint(f);
    return (b & 0x80000000u) ? ~b : (b | 0x80000000u);
}

// ---------------- main kernel: MFMA screen + rare exact recheck + rotation ----------------
__global__ __launch_bounds__(BLKT, 3) void vq_main(
    const float* __restrict__ x, const float* __restrict__ cb,
    float* __restrict__ out_rot, float* __restrict__ out_idx,
    float* __restrict__ ws_hist, float* __restrict__ out_cnt, int use_ws)
{
    __shared__ unsigned int cbh[KC][20];   // bf16-hi codebook, 80B pitch (16B aligned)
    __shared__ unsigned int cbl[KC][20];   // bf16-lo
    __shared__ float c2s[KC];              // ||c||^2 exact pairwise
    __shared__ float hist[KC];
    __shared__ float xs[TPB][36];          // x tile fp32, 144B pitch
    __shared__ float x2w[TPB];             // exact ||x||^2
    __shared__ int      win[4][16];        // per-wave winners
    __shared__ unsigned dmin[4][16];       // flagged-row exact-min keys
    __shared__ unsigned cwin[4][16];       // flagged-row winning code
    // total 53248 B -> 3 blocks/CU

    const int tid  = threadIdx.x;
    const int lane = tid & 63;
    const int w    = tid >> 6;

    // ---- init: c2 exact (numpy pairwise) + bf16 hi/lo split (round-5 verified) ----
    {
#pragma clang fp contract(off)
        const float4* cb4 = (const float4*)(cb + (size_t)tid * D);
        float4 r[8];
#pragma unroll
        for (int j = 0; j < 8; j++) r[j] = cb4[j];
        float v[32];
#pragma unroll
        for (int j = 0; j < 8; j++) {
            v[4*j+0] = r[j].x; v[4*j+1] = r[j].y; v[4*j+2] = r[j].z; v[4*j+3] = r[j].w;
        }
        float t[32];
#pragma unroll
        for (int k = 0; k < 32; k++) t[k] = v[k] * v[k];
        float pr[8];
#pragma unroll
        for (int j = 0; j < 8; j++)
            pr[j] = ((t[j] + t[j + 8]) + t[j + 16]) + t[j + 24];
        c2s[tid] = ((pr[0] + pr[1]) + (pr[2] + pr[3])) + ((pr[4] + pr[5]) + (pr[6] + pr[7]));

        unsigned int hp[16], lp[16];
#pragma unroll
        for (int q = 0; q < 16; q++) { hp[q] = 0u; lp[q] = 0u; }
#pragma unroll
        for (int j = 0; j < 32; j++) {
            unsigned short h = f32_to_bf16_rne(v[j]);
            float lo = v[j] - bf16_to_f32(h);
            unsigned short l = f32_to_bf16_rne(lo);
            hp[j >> 1] |= ((unsigned int)h) << (16 * (j & 1));
            lp[j >> 1] |= ((unsigned int)l) << (16 * (j & 1));
        }
#pragma unroll
        for (int q = 0; q < 4; q++) {
            ((uint4*)&cbh[tid][0])[q] = make_uint4(hp[4*q], hp[4*q+1], hp[4*q+2], hp[4*q+3]);
            ((uint4*)&cbl[tid][0])[q] = make_uint4(lp[4*q], lp[4*q+1], lp[4*q+2], lp[4*q+3]);
        }
        hist[tid] = 0.f;
    }
    __syncthreads();

    const int col = lane & 15;     // code column within tile / A token row
    const int kc  = lane >> 4;     // k-chunk 0..3

    float c2r[16];
#pragma unroll
    for (int t = 0; t < 16; t++) c2r[t] = c2s[t * 16 + col];

    const int stok = tid >> 2;     // staging/epilogue token (block-level 0..63)
    const int ssub = tid & 3;      // dim slice 0..3

    // ---- prologue prefetch ----
    float4 aC0, aC1;
    {
        const float4* xg = (const float4*)(x + (size_t)blockIdx.x * (TPB * D) + (size_t)tid * 8);
        aC0 = xg[0]; aC1 = xg[1];
    }

    for (int tile = blockIdx.x; tile < NTILES; tile += gridDim.x) {
        const int nt = tile + gridDim.x;
        float4 aN0 = aC0, aN1 = aC1;
        if (nt < NTILES) {
            const float4* xg = (const float4*)(x + (size_t)nt * (TPB * D) + (size_t)tid * 8);
            aN0 = xg[0]; aN1 = xg[1];
        }
        const int tb = tile * TPB;

        // ---- stage x tile (wave-private rows; no barrier needed anywhere in loop) ----
        *(float4*)&xs[stok][ssub * 8]     = aC0;
        *(float4*)&xs[stok][ssub * 8 + 4] = aC1;

        // ---- exact ||x||^2 from registers (round-1 verified pairwise pattern) ----
        {
#pragma clang fp contract(off)
            const int base = lane & ~3;
            float sq[8] = {aC0.x*aC0.x, aC0.y*aC0.y, aC0.z*aC0.z, aC0.w*aC0.w,
                           aC1.x*aC1.x, aC1.y*aC1.y, aC1.z*aC1.z, aC1.w*aC1.w};
            float pr[8];
#pragma unroll
            for (int j = 0; j < 8; j++) {
                float t01 = sq[j] + __shfl_xor(sq[j], 1, 64);   // sub0: t[j]+t[j+8]
                float s2  = __shfl(sq[j], base + 2, 64);        // t[j+16]
                float s3  = __shfl(sq[j], base + 3, 64);        // t[j+24]
                pr[j] = (t01 + s2) + s3;
            }
            float v = ((pr[0]+pr[1]) + (pr[2]+pr[3])) + ((pr[4]+pr[5]) + (pr[6]+pr[7]));
            if (ssub == 0) x2w[stok] = v;
        }

        // ---- A fragments (hi/lo bf16) from LDS (wave-private, DS-ordered) ----
        short8 ah, al;
        {
            const float4 fa = *(const float4*)&xs[w * 16 + col][kc * 8];
            const float4 fb = *(const float4*)&xs[w * 16 + col][kc * 8 + 4];
            float xf[8] = {fa.x, fa.y, fa.z, fa.w, fb.x, fb.y, fb.z, fb.w};
#pragma unroll
            for (int j = 0; j < 8; j++) {
                unsigned short h = f32_to_bf16_rne(xf[j]);
                float lo = xf[j] - bf16_to_f32(h);
                ah[j] = (short)h;
                al[j] = (short)f32_to_bf16_rne(lo);
            }
        }

        // ---- MFMA screen with (min, 2nd-min, argmin) tracking; scores packed f16 ----
        unsigned sp01[16], sp23[16];
        float m1[4]  = {BIGF, BIGF, BIGF, BIGF};
        float m2v[4] = {BIGF, BIGF, BIGF, BIGF};
        int   bi1[4] = {0x7fffffff, 0x7fffffff, 0x7fffffff, 0x7fffffff};
#pragma unroll
        for (int t = 0; t < 16; ++t) {
            const int code = t * 16 + col;
            const short8 bh = *(const short8*)&cbh[code][kc * 4];
            const short8 bl = *(const short8*)&cbl[code][kc * 4];
            f32x4 acc = {0.f, 0.f, 0.f, 0.f};
            acc = __builtin_amdgcn_mfma_f32_16x16x32_bf16(al, bh, acc, 0, 0, 0);
            acc = __builtin_amdgcn_mfma_f32_16x16x32_bf16(ah, bl, acc, 0, 0, 0);
            acc = __builtin_amdgcn_mfma_f32_16x16x32_bf16(ah, bh, acc, 0, 0, 0);
            float sv[4];
#pragma unroll
            for (int r = 0; r < 4; ++r) {
                sv[r] = __builtin_fmaf(-2.f, acc[r], c2r[t]);
                const bool lt = sv[r] < m1[r];           // strict < : first-min kept
                m2v[r] = lt ? m1[r] : fminf(m2v[r], sv[r]);
                bi1[r] = lt ? code : bi1[r];
                m1[r]  = lt ? sv[r] : m1[r];
            }
            __half2 p01 = __floats2half2_rn(sv[0], sv[1]);
            __half2 p23 = __floats2half2_rn(sv[2], sv[3]);
            sp01[t] = *reinterpret_cast<unsigned*>(&p01);
            sp23[t] = *reinterpret_cast<unsigned*>(&p23);
        }

        // ---- cross-lane (min,2nd,argmin) reduce over the 16 code-lanes ----
#pragma unroll
        for (int m = 1; m < 16; m <<= 1) {
#pragma unroll
            for (int r = 0; r < 4; ++r) {
                const float o1 = __shfl_xor(m1[r],  m, 64);
                const float o2 = __shfl_xor(m2v[r], m, 64);
                const int   ob = __shfl_xor(bi1[r], m, 64);
                const bool take = (o1 < m1[r]) || (o1 == m1[r] && ob < bi1[r]);
                const float big = take ? m1[r] : o1;
                m1[r]  = take ? o1 : m1[r];
                bi1[r] = take ? ob : bi1[r];
                m2v[r] = fminf(big, fminf(m2v[r], o2));
            }
        }

        bool flag[4];
#pragma unroll
        for (int r = 0; r < 4; ++r) flag[r] = (m2v[r] <= m1[r] + MARGIN);

        if (col == 0) {
#pragma unroll
            for (int r = 0; r < 4; ++r) {
                if (flag[r]) { dmin[w][kc*4+r] = 0xFFFFFFFFu; cwin[w][kc*4+r] = 0xFFFFFFFFu; }
                else           win[w][kc*4+r] = bi1[r];   // unique candidate == exact winner
            }
        }
        const bool anyf = flag[0] || flag[1] || flag[2] || flag[3];
        if (__any((int)anyf)) {
            // pass A: exact distance (reference-exact chain), atomicMin on monotone key
#pragma unroll
            for (int t = 0; t < 16; ++t) {
                const __half2 h01 = *reinterpret_cast<const __half2*>(&sp01[t]);
                const __half2 h23 = *reinterpret_cast<const __half2*>(&sp23[t]);
                const float u[4] = {__low2float(h01), __high2float(h01),
                                    __low2float(h23), __high2float(h23)};
#pragma unroll
                for (int r = 0; r < 4; ++r)
                    if (flag[r] && u[r] <= m1[r] + MARGIN) {
                        const int trow = kc * 4 + r;
                        const int grow = w * 16 + trow;
                        const int code = t * 16 + col;
                        const float* crow = cb + (size_t)code * D;
                        float acc = 0.f;
#pragma unroll
                        for (int q = 0; q < 8; ++q) {
                            const float4 xq = *(const float4*)&xs[grow][q * 4];
                            const float4 cq = *(const float4*)&crow[q * 4];
                            acc = __builtin_fmaf(xq.x, cq.x, acc);
                            acc = __builtin_fmaf(xq.y, cq.y, acc);
                            acc = __builtin_fmaf(xq.z, cq.z, acc);
                            acc = __builtin_fmaf(xq.w, cq.w, acc);
                        }
                        const float t2 = x2w[grow] - 2.0f * acc;   // 2*acc exact
                        const float dd = t2 + c2s[code];
                        atomicMin(&dmin[w][trow], fkey(dd));
                    }
            }
            // pass B: recompute (deterministic), lowest code among exact-bit ties
#pragma unroll
            for (int t = 0; t < 16; ++t) {
                const __half2 h01 = *reinterpret_cast<const __half2*>(&sp01[t]);
                const __half2 h23 = *reinterpret_cast<const __half2*>(&sp23[t]);
                const float u[4] = {__low2float(h01), __high2float(h01),
                                    __low2float(h23), __high2float(h23)};
#pragma unroll
                for (int r = 0; r < 4; ++r)
                    if (flag[r] && u[r] <= m1[r] + MARGIN) {
                        const int trow = kc * 4 + r;
                        const int grow = w * 16 + trow;
                        const int code = t * 16 + col;
                        const float* crow = cb + (size_t)code * D;
                        float acc = 0.f;
#pragma unroll
                        for (int q = 0; q < 8; ++q) {
                            const float4 xq = *(const float4*)&xs[grow][q * 4];
                            const float4 cq = *(const float4*)&crow[q * 4];
                            acc = __builtin_fmaf(xq.x, cq.x, acc);
                            acc = __builtin_fmaf(xq.y, cq.y, acc);
                            acc = __builtin_fmaf(xq.z, cq.z, acc);
                            acc = __builtin_fmaf(xq.w, cq.w, acc);
                        }
                        const float t2 = x2w[grow] - 2.0f * acc;
                        const float dd = t2 + c2s[code];
                        if (fkey(dd) == dmin[w][trow])
                            atomicMin(&cwin[w][trow], (unsigned)code);
                    }
            }
            if (col == 0) {
#pragma unroll
                for (int r = 0; r < 4; ++r)
                    if (flag[r]) win[w][kc*4+r] = (int)cwin[w][kc*4+r];
            }
        }

        // ---- rotation epilogue (verified arithmetic; x from this thread's own regs) ----
        {
            const size_t gtok = (size_t)tb + stok;
            const int bi = win[w][lane >> 2];
            const float4* cg = (const float4*)(cb + (size_t)bi * D + ssub * 8);
            const float4 ca = cg[0], cbv = cg[1];

            float xs8[8] = {aC0.x, aC0.y, aC0.z, aC0.w, aC1.x, aC1.y, aC1.z, aC1.w};
            float cs8[8] = {ca.x, ca.y, ca.z, ca.w, cbv.x, cbv.y, cbv.z, cbv.w};

            float px2 = 0.f, pc2 = 0.f;
#pragma unroll
            for (int j = 0; j < 8; j++) { px2 = fmaf(xs8[j], xs8[j], px2); pc2 = fmaf(cs8[j], cs8[j], pc2); }
            float x2 = px2 + __shfl_xor(px2, 1, 64); x2 += __shfl_xor(x2, 2, 64);
            float c2 = pc2 + __shfl_xor(pc2, 1, 64); c2 += __shfl_xor(c2, 2, 64);
            const float inx = 1.f / fmaxf(sqrtf(x2), EPSF);
            const float inc = 1.f / fmaxf(sqrtf(c2), EPSF);

            float us8[8], qs8[8], ws8[8];
            float pw2 = 0.f;
#pragma unroll
            for (int j = 0; j < 8; j++) {
                us8[j] = xs8[j] * inx;
                qs8[j] = cs8[j] * inc;
                ws8[j] = us8[j] + qs8[j];
                pw2 = fmaf(ws8[j], ws8[j], pw2);
            }
            float w2 = pw2 + __shfl_xor(pw2, 1, 64); w2 += __shfl_xor(w2, 2, 64);
            const float inw = 1.f / fmaxf(sqrtf(w2), EPSF);

            float pew = 0.f, peu = 0.f;
#pragma unroll
            for (int j = 0; j < 8; j++) {
                ws8[j] *= inw;
                pew = fmaf(xs8[j], ws8[j], pew);
                peu = fmaf(xs8[j], us8[j], peu);
            }
            float ew = pew + __shfl_xor(pew, 1, 64); ew += __shfl_xor(ew, 2, 64);
            float eu = peu + __shfl_xor(peu, 1, 64); eu += __shfl_xor(eu, 2, 64);

            float ro[8];
#pragma unroll
            for (int j = 0; j < 8; j++)
                ro[j] = xs8[j] - 2.f * ew * ws8[j] + 2.f * eu * qs8[j];

            float4* og = (float4*)(out_rot + gtok * D + ssub * 8);
            og[0] = make_float4(ro[0], ro[1], ro[2], ro[3]);
            og[1] = make_float4(ro[4], ro[5], ro[6], ro[7]);

            if (ssub == 0) {
                out_idx[gtok] = (float)bi;
                atomicAdd(&hist[bi], 1.f);
            }
        }

        aC0 = aN0; aC1 = aN1;
    }

    __syncthreads();
    // ---- flush per-block histogram ----
    if (use_ws) ws_hist[(size_t)blockIdx.x * KC + tid] = hist[tid];
    else        atomicAdd(&out_cnt[tid], hist[tid]);
}

// ---------------- tiny reduce: 768 block-partials -> 256 counts ----------------
__global__ __launch_bounds__(256) void vq_reduce(const float* __restrict__ ws,
                                                 float* __restrict__ out_cnt)
{
    const int c = blockIdx.x * 8 + (threadIdx.x >> 5);  // code
    const int l = threadIdx.x & 31;                     // lane within code-group
    float s = 0.f;
    for (int b = l; b < NBLK; b += 32) s += ws[(size_t)b * KC + c];
#pragma unroll
    for (int m = 1; m < 32; m <<= 1) s += __shfl_xor(s, m, 64);
    if (l == 0) out_cnt[c] = s;
}

extern "C" void kernel_launch(void* const* d_in, const int* in_sizes, int n_in,
                              void* d_out, int out_size, void* d_ws, size_t ws_size,
                              hipStream_t stream)
{
    const float* x  = (const float*)d_in[0];
    const float* cb = (const float*)d_in[1];
    float* out      = (float*)d_out;
    float* out_rot  = out;                                   // [524288*32]
    float* out_idx  = out + (size_t)N_TOK * D;               // [524288] (indices as float)
    float* out_cnt  = out_idx + N_TOK;                       // [256]

    const size_t ws_need = (size_t)NBLK * KC * sizeof(float);
    const int use_ws = (ws_size >= ws_need) ? 1 : 0;
    if (!use_ws) hipMemsetAsync(out_cnt, 0, KC * sizeof(float), stream);

    vq_main<<<NBLK, BLKT, 0, stream>>>(x, cb, out_rot, out_idx,
                                       (float*)d_ws, out_cnt, use_ws);
    if (use_ws) vq_reduce<<<32, 256, 0, stream>>>((const float*)d_ws, out_cnt);
}